// Round 1
// baseline (259.578 us; speedup 1.0000x reference)
//
#include <hip/hip_runtime.h>
#include <hip/hip_bf16.h>
#include <math.h>

#define C_CH 8
#define H_DIM 512
#define BS 32768            // B*S
#define K_DIM 4096          // C*H
#define EPS 1e-5f

#define TM 64
#define TK 32
#define NKT (K_DIM / TK)    // 128 K-tiles, processed in 32 groups of 4
#define TMTK (TM * TK)

typedef __bf16 bf16x8 __attribute__((ext_vector_type(8)));
typedef __bf16 bf16x4 __attribute__((ext_vector_type(4)));
typedef float  floatx4 __attribute__((ext_vector_type(4)));

// tanh-form GELU, exp2-folded: gelu(v) ~= v * sigmoid(1.5957691*(v+0.044715 v^3))
// constants pre-multiplied by log2(e); max abs dev from exact erf-gelu ~3e-4.
__device__ __forceinline__ float gelu_fast(float v) {
    float x2 = v * fmaf(v * v, 0.102943215f, 2.30220815f);   // x*log2e
    float e = __builtin_amdgcn_exp2f(-x2);
    return v * __builtin_amdgcn_rcpf(1.0f + e);
}

// Prep kernel, grid = 1024 + 8 blocks x 256 threads.
// Blocks [0,1024): mod_w fp32 [512][4096] -> bf16 workspace in MFMA B-fragment
//   chunk layout: chunk(kt 0..127, ntile 0..31) of 64 lanes x 16B; lane l holds
//   B[col = ntile*16 + (l&15)][k = kt*32 + (l>>4)*8 + i], i=0..7.
// Blocks [1024,1032): per-channel encoder-LN fold (c = blockIdx-1024):
//   Wf[c][j] = gamma*(w - mean(w)), Bf[c][j] = gamma*(b - mean(b)),
//   st[c] = {var_w, 2*cov_wb, var_b} so the fused kernel's per-row work is
//   q = rsqrt(x^2 vw + x*2cwb + vb + eps), p = x*q, and
//   A[row][c*512+j] = gelu(p*Wf + q*Bf + enc_beta).
__global__ __launch_bounds__(256) void prep_kernel(
    const float* __restrict__ w, __bf16* __restrict__ o,
    const float* __restrict__ enc_w, const float* __restrict__ enc_b,
    const float* __restrict__ enc_gamma,
    float* __restrict__ Wf, float* __restrict__ Bf, float* __restrict__ st)
{
    __shared__ float red[4][5];
    if (blockIdx.x < 1024) {
        int gtid  = blockIdx.x * 256 + threadIdx.x;   // 0..262143
        int lane  = gtid & 63;
        int chunk = gtid >> 6;                        // 0..4095
        int kt    = chunk >> 5;
        int ntile = chunk & 31;
        int col   = ntile * 16 + (lane & 15);
        int k     = kt * 32 + (lane >> 4) * 8;
        const float* src = w + (size_t)col * K_DIM + k;
        float4 a = *(const float4*)src;
        float4 b = *(const float4*)(src + 4);
        bf16x8 h;
        h[0] = (__bf16)a.x; h[1] = (__bf16)a.y; h[2] = (__bf16)a.z; h[3] = (__bf16)a.w;
        h[4] = (__bf16)b.x; h[5] = (__bf16)b.y; h[6] = (__bf16)b.z; h[7] = (__bf16)b.w;
        *(bf16x8*)(o + (size_t)gtid * 8) = h;
    } else {
        const int c = blockIdx.x - 1024;              // 0..7
        const int t = threadIdx.x;                    // 0..255
        const float* wp = enc_w + c * H_DIM;
        const float* bp = enc_b + c * H_DIM;
        const float* gp = enc_gamma + c * H_DIM;
        float w0 = wp[t], w1 = wp[t + 256];
        float b0 = bp[t], b1 = bp[t + 256];
        float sw  = w0 + w1;
        float sb  = b0 + b1;
        float sww = fmaf(w0, w0, w1 * w1);
        float sbb = fmaf(b0, b0, b1 * b1);
        float swb = fmaf(w0, b0, w1 * b1);
        #pragma unroll
        for (int off = 32; off; off >>= 1) {
            sw  += __shfl_xor(sw,  off);
            sb  += __shfl_xor(sb,  off);
            sww += __shfl_xor(sww, off);
            sbb += __shfl_xor(sbb, off);
            swb += __shfl_xor(swb, off);
        }
        int wv = t >> 6, ln = t & 63;
        if (ln == 0) {
            red[wv][0] = sw;  red[wv][1] = sb;  red[wv][2] = sww;
            red[wv][3] = sbb; red[wv][4] = swb;
        }
        __syncthreads();
        float tsw  = red[0][0] + red[1][0] + red[2][0] + red[3][0];
        float tsb  = red[0][1] + red[1][1] + red[2][1] + red[3][1];
        float tsww = red[0][2] + red[1][2] + red[2][2] + red[3][2];
        float tsbb = red[0][3] + red[1][3] + red[2][3] + red[3][3];
        float tswb = red[0][4] + red[1][4] + red[2][4] + red[3][4];
        const float inv = 1.0f / (float)H_DIM;
        float mw = tsw * inv, mb = tsb * inv;
        if (t == 0) {
            st[c * 4 + 0] = tsww * inv - mw * mw;           // var_w
            st[c * 4 + 1] = 2.0f * (tswb * inv - mw * mb);  // 2*cov
            st[c * 4 + 2] = tsbb * inv - mb * mb;           // var_b
        }
        float g0 = gp[t], g1 = gp[t + 256];
        Wf[c * H_DIM + t]       = g0 * (w0 - mw);
        Wf[c * H_DIM + t + 256] = g1 * (w1 - mw);
        Bf[c * H_DIM + t]       = g0 * (b0 - mb);
        Bf[c * H_DIM + t + 256] = g1 * (b1 - mb);
    }
}

// Fused: analytic enc-LN -> gelu -> GEMM(mod_w^T) -> +mod_b -> LayerNorm -> gelu.
// 512 threads / 8 waves, wave-tile 64x64. One barrier per 4 K-tiles: A staged
// into 2 groups x 4 sub-tile LDS buffers; stageA(group g+1) interleaved with
// MFMA(group g). B frags stream global(L2)->VGPR with P/Q rotation.
template <int USE_WS>
__global__ __launch_bounds__(512, 4) void fused_gemm_kernel(
    const float* __restrict__ x,
    const float* __restrict__ enc_w,
    const float* __restrict__ enc_b,
    const float* __restrict__ enc_gamma,
    const float* __restrict__ enc_beta,
    const float* __restrict__ mod_w,      // fp32 fallback
    const __bf16* __restrict__ Wb,        // bf16 frag-layout (workspace)
    const float* __restrict__ Wf,         // folded gamma*(w-mw)   (workspace)
    const float* __restrict__ Bf,         // folded gamma*(b-mb)   (workspace)
    const float* __restrict__ st,         // per-channel {vw,2cwb,vb} (workspace)
    const float* __restrict__ mod_b,
    const float* __restrict__ mod_gamma,
    const float* __restrict__ mod_beta,
    float* __restrict__ out)
{
    __shared__ float stats[C_CH][5];            // legacy path only
    __shared__ float pS[C_CH][TM];
    __shared__ float qS[C_CH][TM];
    __shared__ float rS[C_CH][TM];              // legacy path only
    __shared__ __align__(16) __bf16 Als[2 * 4 * TMTK];   // 32 KB, swizzled chunks
    __shared__ float redS[TM][8];
    __shared__ float redQ[TM][8];
    __shared__ float muS[TM];
    __shared__ float invS[TM];

    const int tid  = threadIdx.x;
    const int wave = tid >> 6;        // 0..7
    const int lane = tid & 63;
    const int row0 = blockIdx.x * TM;

    if (USE_WS) {
        // ---- per-(channel,row) p,q from precomputed channel stats ----
        int c = wave;                 // 512 threads == 8 channels x 64 rows
        int m = lane;
        float xv = x[c * BS + row0 + m];
        float vw = st[c * 4 + 0], cwb2 = st[c * 4 + 1], vb = st[c * 4 + 2];
        float q = rsqrtf(fmaf(xv, fmaf(xv, vw, cwb2), vb) + EPS);
        pS[c][m] = xv * q;
        qS[c][m] = q;
    } else {
        // ---- legacy: in-kernel stats, then p,q,r ----
        {
            const int c = wave;
            float sw = 0.f, sb = 0.f, sww = 0.f, sbb = 0.f, swb = 0.f;
            for (int j = lane; j < H_DIM; j += 64) {
                float w = enc_w[c * H_DIM + j];
                float b = enc_b[c * H_DIM + j];
                sw += w; sb += b;
                sww = fmaf(w, w, sww);
                sbb = fmaf(b, b, sbb);
                swb = fmaf(w, b, swb);
            }
            #pragma unroll
            for (int off = 32; off; off >>= 1) {
                sw  += __shfl_xor(sw,  off);
                sb  += __shfl_xor(sb,  off);
                sww += __shfl_xor(sww, off);
                sbb += __shfl_xor(sbb, off);
                swb += __shfl_xor(swb, off);
            }
            if (lane == 0) {
                const float inv = 1.0f / (float)H_DIM;
                float mw = sw * inv, mb = sb * inv;
                stats[c][0] = mw;
                stats[c][1] = mb;
                stats[c][2] = sww * inv - mw * mw;
                stats[c][3] = sbb * inv - mb * mb;
                stats[c][4] = swb * inv - mw * mb;
            }
        }
        __syncthreads();
        {
            int c = wave;
            int m = lane;
            float xv = x[c * BS + row0 + m];
            float mw = stats[c][0], mb = stats[c][1];
            float vw = stats[c][2], vb = stats[c][3], cwb = stats[c][4];
            float var = fmaf(xv, fmaf(xv, vw, 2.0f * cwb), vb);
            float q = rsqrtf(var + EPS);
            float p = xv * q;
            pS[c][m] = p;
            qS[c][m] = q;
            rS[c][m] = -fmaf(p, mw, q * mb);
        }
    }
    __syncthreads();

    const int wn = wave;             // wave tile: 64 rows x 64 cols
    const int lr = lane & 15;
    const int lq = lane >> 4;

    // stageA decomposition: tid = row*8 + kq*2 + half (4 elems / 8B per thread)
    const int arow  = tid >> 3;      // 0..63
    const int akq   = (tid >> 1) & 3;
    const int ahalf = tid & 1;
    const int wchunk = arow * 4 + (akq ^ ((arow >> 1) & 3));   // XOR bank swizzle

    floatx4 acc[4][4];
    #pragma unroll
    for (int i = 0; i < 4; ++i)
        #pragma unroll
        for (int j = 0; j < 4; ++j)
            acc[i][j] = (floatx4){0.f, 0.f, 0.f, 0.f};

    // ---- A-stage (folded): v = p*Wf + q*Bf + beta; gelu; one 8B half-chunk ----
    // p,q hoisted to registers (channel constant across a 4-tile group).
    auto stageA2 = [&](int ktn, __bf16* dst, float p, float q) {
        const int j0 = ktn * TK + akq * 8 + ahalf * 4;   // Wf/Bf/beta are [C*H]
        float4 w = *(const float4*)(Wf + j0);
        float4 b = *(const float4*)(Bf + j0);
        float4 e = *(const float4*)(enc_beta + j0);
        float fw[4] = {w.x, w.y, w.z, w.w};
        float fb[4] = {b.x, b.y, b.z, b.w};
        float fe[4] = {e.x, e.y, e.z, e.w};
        bf16x4 hv;
        #pragma unroll
        for (int i = 0; i < 4; ++i) {
            float v = fmaf(p, fw[i], fmaf(q, fb[i], fe[i]));
            hv[i] = (__bf16)gelu_fast(v);
        }
        *(bf16x4*)(dst + wchunk * 8 + ahalf * 4) = hv;
    };

    // ---- legacy A-stage: 4 param arrays + per-call LDS p/q/r reads ----
    auto stageA_legacy = [&](int ktn, __bf16* dst) {
        const int k0 = ktn * TK;
        const int c  = k0 >> 9;
        const int j0 = c * H_DIM + (k0 & (H_DIM - 1)) + akq * 8 + ahalf * 4;
        float p = pS[c][arow], q = qS[c][arow], r = rS[c][arow];
        float4 w = *(const float4*)(enc_w + j0);
        float4 b = *(const float4*)(enc_b + j0);
        float4 g = *(const float4*)(enc_gamma + j0);
        float4 e = *(const float4*)(enc_beta + j0);
        float fw[4] = {w.x, w.y, w.z, w.w};
        float fb[4] = {b.x, b.y, b.z, b.w};
        float fg[4] = {g.x, g.y, g.z, g.w};
        float fe[4] = {e.x, e.y, e.z, e.w};
        bf16x4 hv;
        #pragma unroll
        for (int i = 0; i < 4; ++i) {
            float t = fmaf(p, fw[i], fmaf(q, fb[i], r));
            float v = fmaf(t, fg[i], fe[i]);
            hv[i] = (__bf16)gelu_fast(v);
        }
        *(bf16x4*)(dst + wchunk * 8 + ahalf * 4) = hv;
    };

    // ---- B-frag loader: 2 frags (one n-half of the wave's 64 cols) ----
    const __bf16* baseB = Wb + ((size_t)(wn * 4) * 64 + lane) * 8;
    auto loadB = [&](int ktn, int half, bf16x8* dst) {
        if (USE_WS) {
            const __bf16* bp = baseB + ktn * 16384 + half * 1024;
            dst[0] = *(const bf16x8*)(bp);
            dst[1] = *(const bf16x8*)(bp + 512);
        } else {
            const int kk = ktn * 32 + lq * 8;
            #pragma unroll
            for (int nt = 0; nt < 2; ++nt) {
                int col = wn * 64 + (half * 2 + nt) * 16 + lr;
                const float* src = mod_w + (size_t)col * K_DIM + kk;
                float4 a = *(const float4*)src;
                float4 b = *(const float4*)(src + 4);
                bf16x8 h;
                h[0] = (__bf16)a.x; h[1] = (__bf16)a.y; h[2] = (__bf16)a.z; h[3] = (__bf16)a.w;
                h[4] = (__bf16)b.x; h[5] = (__bf16)b.y; h[6] = (__bf16)b.z; h[7] = (__bf16)b.w;
                dst[nt] = h;
            }
        }
    };

    bf16x8 bfrP[2], bfrQ[2];
    loadB(0, 0, bfrP);          // prologue: first half of k-tile-0 B in flight
    if (USE_WS) {
        float p0 = pS[0][arow], q0 = qS[0][arow];
        #pragma unroll
        for (int sub = 0; sub < 4; ++sub)
            stageA2(sub, Als + sub * TMTK, p0, q0);
    } else {
        #pragma unroll
        for (int sub = 0; sub < 4; ++sub)
            stageA_legacy(sub, Als + sub * TMTK);
    }
    __syncthreads();

    for (int g = 0; g < NKT / 4; ++g) {
        const __bf16* cur = Als + (g & 1) * (4 * TMTK);
        __bf16*       nxt = Als + ((g + 1) & 1) * (4 * TMTK);
        const bool haveNext = (g + 1 < NKT / 4);

        float pC = 0.f, qC = 0.f;
        if (USE_WS && haveNext) {
            const int cn = (g + 1) >> 2;   // channel of next group's k-range
            pC = pS[cn][arow];
            qC = qS[cn][arow];
        }

        #pragma unroll
        for (int sub = 0; sub < 4; ++sub) {
            const int kt = g * 4 + sub;

            // second-half B for this k-tile (covered by stageA VALU below)
            loadB(kt, 1, bfrQ);

            // stage one sub-tile of the NEXT group's A
            if (haveNext) {
                if (USE_WS) stageA2(kt + 4, nxt + sub * TMTK, pC, qC);
                else        stageA_legacy(kt + 4, nxt + sub * TMTK);
            }

            // A fragment reads (swizzled, 2-way conflict = free)
            const __bf16* Acur = cur + sub * TMTK;
            bf16x8 af[4];
            #pragma unroll
            for (int mt = 0; mt < 4; ++mt) {
                int row = mt * 16 + lr;
                int chunk = row * 4 + (lq ^ ((row >> 1) & 3));
                af[mt] = *(const bf16x8*)(Acur + chunk * 8);
            }

            // MFMA half 1: bfrP (issued one phase earlier)
            #pragma unroll
            for (int mt = 0; mt < 4; ++mt)
                #pragma unroll
                for (int nt = 0; nt < 2; ++nt)
                    acc[mt][nt] = __builtin_amdgcn_mfma_f32_16x16x32_bf16(
                        af[mt], bfrP[nt], acc[mt][nt], 0, 0, 0);

            // first-half B for the NEXT k-tile
            if (kt + 1 < NKT) loadB(kt + 1, 0, bfrP);

            // MFMA half 2: bfrQ
            #pragma unroll
            for (int mt = 0; mt < 4; ++mt)
                #pragma unroll
                for (int nt = 0; nt < 2; ++nt)
                    acc[mt][nt + 2] = __builtin_amdgcn_mfma_f32_16x16x32_bf16(
                        af[mt], bfrQ[nt], acc[mt][nt + 2], 0, 0, 0);
        }
        __syncthreads();      // one barrier per 4 k-tiles
    }

    // ---- fused epilogue: +mod_b, LayerNorm over 512 cols, gelu, store ----
    float mbv[4], gv[4], bev[4];
    #pragma unroll
    for (int nt = 0; nt < 4; ++nt) {
        int col = wn * 64 + nt * 16 + lr;
        mbv[nt] = mod_b[col];
        gv[nt]  = mod_gamma[col];
        bev[nt] = mod_beta[col];
    }
    #pragma unroll
    for (int mt = 0; mt < 4; ++mt)
        #pragma unroll
        for (int nt = 0; nt < 4; ++nt)
            #pragma unroll
            for (int r = 0; r < 4; ++r)
                acc[mt][nt][r] += mbv[nt];

    // per-row partial sums within this wave's 64 cols
    #pragma unroll
    for (int mt = 0; mt < 4; ++mt) {
        #pragma unroll
        for (int r = 0; r < 4; ++r) {
            float s = 0.f, ss = 0.f;
            #pragma unroll
            for (int nt = 0; nt < 4; ++nt) {
                float y = acc[mt][nt][r];
                s += y;
                ss = fmaf(y, y, ss);
            }
            #pragma unroll
            for (int off = 1; off < 16; off <<= 1) {
                s  += __shfl_xor(s,  off);
                ss += __shfl_xor(ss, off);
            }
            if (lr == 0) {
                int row = mt * 16 + lq * 4 + r;
                redS[row][wn] = s;
                redQ[row][wn] = ss;
            }
        }
    }
    __syncthreads();
    if (tid < TM) {
        float s = 0.f, ss = 0.f;
        #pragma unroll
        for (int w = 0; w < 8; ++w) {
            s  += redS[tid][w];
            ss += redQ[tid][w];
        }
        const float inv_n = 1.0f / (float)H_DIM;
        float mu  = s * inv_n;
        float var = ss * inv_n - mu * mu;
        muS[tid]  = mu;
        invS[tid] = rsqrtf(var + EPS);
    }
    __syncthreads();

    #pragma unroll
    for (int mt = 0; mt < 4; ++mt) {
        #pragma unroll
        for (int r = 0; r < 4; ++r) {
            int row = mt * 16 + lq * 4 + r;
            float mu  = muS[row];
            float inv = invS[row];
            float* op = out + (size_t)(row0 + row) * H_DIM;
            #pragma unroll
            for (int nt = 0; nt < 4; ++nt) {
                int col = wn * 64 + nt * 16 + lr;
                float t = fmaf((acc[mt][nt][r] - mu) * inv, gv[nt], bev[nt]);
                op[col] = gelu_fast(t);
            }
        }
    }
}

extern "C" void kernel_launch(void* const* d_in, const int* in_sizes, int n_in,
                              void* d_out, int out_size, void* d_ws, size_t ws_size,
                              hipStream_t stream) {
    const float* x         = (const float*)d_in[0];
    const float* enc_w     = (const float*)d_in[1];
    const float* enc_b     = (const float*)d_in[2];
    const float* enc_gamma = (const float*)d_in[3];
    const float* enc_beta  = (const float*)d_in[4];
    const float* mod_w     = (const float*)d_in[5];
    const float* mod_b     = (const float*)d_in[6];
    const float* mod_gamma = (const float*)d_in[7];
    const float* mod_beta  = (const float*)d_in[8];
    float* out = (float*)d_out;

    const size_t wb_bytes = (size_t)H_DIM * K_DIM * sizeof(__bf16);   // 4 MB
    const size_t wf_off   = wb_bytes;
    const size_t bf_off   = wf_off + (size_t)C_CH * H_DIM * sizeof(float);  // +16 KB
    const size_t st_off   = bf_off + (size_t)C_CH * H_DIM * sizeof(float);  // +16 KB
    const size_t need     = st_off + (size_t)C_CH * 4 * sizeof(float);

    int use_ws = (ws_size >= need) ? 1 : 0;
    __bf16* Wb = (__bf16*)d_ws;
    float*  Wf = (float*)((char*)d_ws + wf_off);
    float*  Bf = (float*)((char*)d_ws + bf_off);
    float*  st = (float*)((char*)d_ws + st_off);

    if (use_ws) {
        prep_kernel<<<1024 + C_CH, 256, 0, stream>>>(
            mod_w, Wb, enc_w, enc_b, enc_gamma, Wf, Bf, st);
        fused_gemm_kernel<1><<<BS / TM, 512, 0, stream>>>(
            x, enc_w, enc_b, enc_gamma, enc_beta, mod_w, Wb, Wf, Bf, st,
            mod_b, mod_gamma, mod_beta, out);
    } else {
        fused_gemm_kernel<0><<<BS / TM, 512, 0, stream>>>(
            x, enc_w, enc_b, enc_gamma, enc_beta, mod_w, Wb,
            (const float*)0, (const float*)0, (const float*)0,
            mod_b, mod_gamma, mod_beta, out);
    }
}